// Round 9
// baseline (740.114 us; speedup 1.0000x reference)
//
#include <hip/hip_runtime.h>
#include <stdint.h>

typedef short bf16x8 __attribute__((ext_vector_type(8)));
typedef float f32x4 __attribute__((ext_vector_type(4)));

__device__ __forceinline__ unsigned short f2bf(float f) {
  union { float f; unsigned int i; } v; v.f = f;
  unsigned int r = v.i + 0x7FFF + ((v.i >> 16) & 1);
  return (unsigned short)(r >> 16);
}
__device__ __forceinline__ void gload_lds16(const void* g, void* l) {
  __builtin_amdgcn_global_load_lds(
      (const __attribute__((address_space(1))) unsigned int*)g,
      (__attribute__((address_space(3))) unsigned int*)l,
      16, 0, 0);
}

// ---------------- convert f32 weights -> bf16 (Whh0, Wih1, Whh1, Wout) ----------------
__global__ __launch_bounds__(256) void k_cvt(const float* __restrict__ s0, const float* __restrict__ s1,
                                             const float* __restrict__ s2, const float* __restrict__ s3,
                                             unsigned short* __restrict__ d0, unsigned short* __restrict__ d1,
                                             unsigned short* __restrict__ d2, unsigned short* __restrict__ d3) {
  int j = blockIdx.x * 256 + threadIdx.x;   // 6656*256 = 1,703,936 vec8 jobs exactly
  const float* s; unsigned short* d; int o;
  if (j < 524288)       { s = s0; d = d0; o = j; }
  else if (j < 1048576) { s = s1; d = d1; o = j - 524288; }
  else if (j < 1572864) { s = s2; d = d2; o = j - 1048576; }
  else                  { s = s3; d = d3; o = j - 1572864; }
  size_t off = (size_t)o * 8;
  f32x4 v0 = *(const f32x4*)(s + off);
  f32x4 v1 = *(const f32x4*)(s + off + 4);
  bf16x8 r;
#pragma unroll
  for (int k = 0; k < 4; k++) { r[k] = (short)f2bf(v0[k]); r[4 + k] = (short)f2bf(v1[k]); }
  *(bf16x8*)(d + off) = r;
}

// ---------------- prep: embedding gather (f32) + zero state + zero flags ----------------
__global__ __launch_bounds__(256) void k_prep(const int* __restrict__ ys,
                                              const float* __restrict__ embed,
                                              float* __restrict__ eys,
                                              float* __restrict__ h0h, float* __restrict__ h1h,
                                              int* __restrict__ flags) {
  int idx = blockIdx.x * 256 + threadIdx.x;   // 16384 threads
  int row = idx >> 6;
  int e = (idx & 63) * 8;
  int y = ys[row];
  f32x4 v0 = {0.f, 0.f, 0.f, 0.f}, v1 = {0.f, 0.f, 0.f, 0.f};
  if (y != 0) {
    v0 = *(const f32x4*)(embed + (size_t)y * 512 + e);
    v1 = *(const f32x4*)(embed + (size_t)y * 512 + e + 4);
  }
  *(f32x4*)(eys + (size_t)row * 512 + e) = v0;
  *(f32x4*)(eys + (size_t)row * 512 + e + 4) = v1;
  if (idx < 4096) { h0h[idx] = 0.f; h1h[idx] = 0.f; }
  if (idx < 64) flags[idx] = 0;
}

// -------- generic small GEMM: C(f32 MxN) = A(f32 MxK) @ W(f32 NxK)^T + b1 + b2 --------
__global__ __launch_bounds__(256) void k_gemm_bias(const float* __restrict__ A,
                                                   const float* __restrict__ W,
                                                   const float* __restrict__ b1,
                                                   const float* __restrict__ b2,
                                                   float* __restrict__ C,
                                                   int M, int N, int K) {
  __shared__ unsigned short Als[64][40];
  __shared__ unsigned short Wls[64][40];
  int tid = threadIdx.x;
  int lane = tid & 63, wid = tid >> 6;
  int mtiles = M >> 6;
  int mt = blockIdx.x % mtiles, nt = blockIdx.x / mtiles;
  int srow = tid >> 2, sseg = tid & 3;
  f32x4 acc[4];
#pragma unroll
  for (int nf = 0; nf < 4; nf++) acc[nf] = (f32x4){0.f, 0.f, 0.f, 0.f};

  for (int kc = 0; kc < K; kc += 32) {
    const float* ap = A + (size_t)(mt * 64 + srow) * K + kc + sseg * 8;
    const float* wp = W + (size_t)(nt * 64 + srow) * K + kc + sseg * 8;
    f32x4 a0 = *(const f32x4*)ap, a1 = *(const f32x4*)(ap + 4);
    f32x4 w0 = *(const f32x4*)wp, w1 = *(const f32x4*)(wp + 4);
    bf16x8 av, wv;
#pragma unroll
    for (int k = 0; k < 4; k++) {
      av[k] = (short)f2bf(a0[k]); av[4 + k] = (short)f2bf(a1[k]);
      wv[k] = (short)f2bf(w0[k]); wv[4 + k] = (short)f2bf(w1[k]);
    }
    __syncthreads();
    *(bf16x8*)(&Als[srow][sseg * 8]) = av;
    *(bf16x8*)(&Wls[srow][sseg * 8]) = wv;
    __syncthreads();
    bf16x8 af = *(const bf16x8*)(&Als[wid * 16 + (lane & 15)][(lane >> 4) * 8]);
#pragma unroll
    for (int nf = 0; nf < 4; nf++) {
      bf16x8 bf = *(const bf16x8*)(&Wls[nf * 16 + (lane & 15)][(lane >> 4) * 8]);
      acc[nf] = __builtin_amdgcn_mfma_f32_16x16x32_bf16(af, bf, acc[nf], 0, 0, 0);
    }
  }
  int rloc = (lane >> 4) * 4;
  int col0 = lane & 15;
#pragma unroll
  for (int nf = 0; nf < 4; nf++) {
    int n = nt * 64 + nf * 16 + col0;
    float bias = 0.f;
    if (b1) bias += b1[n];
    if (b2) bias += b2[n];
#pragma unroll
    for (int r = 0; r < 4; r++) {
      int m = mt * 64 + wid * 16 + rloc + r;
      C[(size_t)m * N + n] = acc[nf][r] + bias;
    }
  }
}

// ---------------- fused LSTM v3: 64 merged blocks, single sync domain ----------------
// 64 blocks x 512 threads (8 waves). Block b owns channels [b*16, b*16+16) of BOTH layers.
// Round p: layer0 step p (p<64) || layer1 step p-1 (p>=1). Both consume h0h[p]; layer1
// also consumes h1h[p-1]. One staged X tile serves both. One flag store + one 64-flag
// poll per round. Weight B-frags (layer0: 64 VGPR, layer1: 128 VGPR) register-resident.
__global__ __launch_bounds__(512, 2) void k_lstm_fused(
    const float* __restrict__ X0,            // (B,U,4096)  eys@Wih0^T + bih0 + bhh0
    float* __restrict__ h0h,                 // (65,B,1024)
    float* __restrict__ h1h,                 // (65,B,1024)
    float* __restrict__ hdec,                // (B,U,1024) f32
    const unsigned short* __restrict__ W_hh0,
    const unsigned short* __restrict__ W_ih1,
    const unsigned short* __restrict__ W_hh1,
    const float* __restrict__ b_ih1,
    const float* __restrict__ b_hh1,
    int* __restrict__ flags) {               // 64 flags
  __shared__ unsigned short X_lds[4][2064];  // 4 batches x 2048 k (+16 pad)
  __shared__ float red0[8][4][16][4];        // 8 KB
  __shared__ float red1[8][4][16][4];        // 8 KB
  __shared__ float gsum[2][4][16][4];        // 2 KB
  int tid = threadIdx.x;
  int lane = tid & 63, w = tid >> 6;
  int bid = blockIdx.x;                      // 0..63
  int base = bid * 16;

  // ---- preload weight B-frags (fragment scheme identical to passing r5-r7 kernel) ----
  bf16x8 wf0[4][4];    // [gate][ks], layer0: K=128 per wave
  bf16x8 wf1[4][8];    // layer1: K=256 per wave (k<1024 -> Wih1, else Whh1)
  int ch = lane & 15;
  int kb0 = w * 128, kb1 = w * 256;
  int klo = (lane >> 4) << 3;
#pragma unroll
  for (int nt = 0; nt < 4; nt++) {
    int grow = nt * 1024 + base + ch;
#pragma unroll
    for (int ks = 0; ks < 4; ks++)
      wf0[nt][ks] = *(const bf16x8*)(W_hh0 + (size_t)grow * 1024 + kb0 + ks * 32 + klo);
#pragma unroll
    for (int ks = 0; ks < 8; ks++) {
      int k = kb1 + ks * 32 + klo;
      const unsigned short* src = (k < 1024) ? (W_ih1 + (size_t)grow * 1024 + k)
                                             : (W_hh1 + (size_t)grow * 1024 + (k - 1024));
      wf1[nt][ks] = *(const bf16x8*)src;
    }
  }

  // gate-thread persistent state: tid<64 -> layer0 (ch=tid>>2, b=tid&3); 64..127 -> layer1
  float creg = 0.f;
  float bs0 = 0.f, bs1 = 0.f, bs2 = 0.f, bs3 = 0.f;
  int gch = (tid & 63) >> 2, gb = tid & 3;
  if (tid >= 64 && tid < 128) {
    int c = base + gch;
    bs0 = b_ih1[c] + b_hh1[c];
    bs1 = b_ih1[1024 + c] + b_hh1[1024 + c];
    bs2 = b_ih1[2048 + c] + b_hh1[2048 + c];
    bs3 = b_ih1[3072 + c] + b_hh1[3072 + c];
  }

  int ar = ch & 3;                           // clamped A-row (batch); D rows 4-15 unused
  for (int p = 0; p <= 64; p++) {
    bool act0 = (p < 64), act1 = (p >= 1);
    // ---- wait: all 64 blocks posted round p-1 (=> h0h[p], h1h[p-1] at IC) ----
    if (p > 0) {
      if (w == 0) {
        while (true) {
          int f = __hip_atomic_load(&flags[lane], __ATOMIC_RELAXED, __HIP_MEMORY_SCOPE_AGENT);
          if (__all(f >= p)) break;
          __builtin_amdgcn_s_sleep(1);
        }
      }
      __syncthreads();
    }
    // ---- stage X = [h0h[p] | h1h[p-1]] as bf16, 4x2048 ----
    {
      int b = tid >> 7, k0 = (tid & 127) * 16;
      if (k0 < 1024 || act1) {
        const float* fsrc = (k0 < 1024) ? (h0h + (size_t)p * 4096 + b * 1024 + k0)
                                        : (h1h + (size_t)(p - 1) * 4096 + b * 1024 + (k0 - 1024));
        const unsigned long long* s8 = (const unsigned long long*)fsrc;
        unsigned long long v[8];
#pragma unroll
        for (int i = 0; i < 8; i++)
          v[i] = __hip_atomic_load(s8 + i, __ATOMIC_RELAXED, __HIP_MEMORY_SCOPE_AGENT);
        bf16x8 r0, r1;
#pragma unroll
        for (int i = 0; i < 4; i++) {
          union { unsigned long long u; float f[2]; } cv; cv.u = v[i];
          r0[2 * i] = (short)f2bf(cv.f[0]); r0[2 * i + 1] = (short)f2bf(cv.f[1]);
        }
#pragma unroll
        for (int i = 0; i < 4; i++) {
          union { unsigned long long u; float f[2]; } cv; cv.u = v[4 + i];
          r1[2 * i] = (short)f2bf(cv.f[0]); r1[2 * i + 1] = (short)f2bf(cv.f[1]);
        }
        *(bf16x8*)&X_lds[b][k0] = r0;
        *(bf16x8*)&X_lds[b][k0 + 8] = r1;
      }
    }
    __syncthreads();

    // ---- layer0 MFMA: gates(16x64) partial over this wave's K=128 ----
    if (act0) {
      f32x4 acc[4];
#pragma unroll
      for (int nt = 0; nt < 4; nt++) acc[nt] = (f32x4){0.f, 0.f, 0.f, 0.f};
#pragma unroll
      for (int ks = 0; ks < 4; ks++) {
        bf16x8 a = *(const bf16x8*)&X_lds[ar][kb0 + ks * 32 + klo];
#pragma unroll
        for (int nt = 0; nt < 4; nt++)
          acc[nt] = __builtin_amdgcn_mfma_f32_16x16x32_bf16(a, wf0[nt][ks], acc[nt], 0, 0, 0);
      }
      if (lane < 16) {
#pragma unroll
        for (int nt = 0; nt < 4; nt++) *(f32x4*)&red0[w][nt][lane][0] = acc[nt];
      }
    }
    // ---- layer1 MFMA: K=256 per wave over combined [h0|h1] ----
    if (act1) {
      f32x4 acc[4];
#pragma unroll
      for (int nt = 0; nt < 4; nt++) acc[nt] = (f32x4){0.f, 0.f, 0.f, 0.f};
#pragma unroll
      for (int ks = 0; ks < 8; ks++) {
        bf16x8 a = *(const bf16x8*)&X_lds[ar][kb1 + ks * 32 + klo];
#pragma unroll
        for (int nt = 0; nt < 4; nt++)
          acc[nt] = __builtin_amdgcn_mfma_f32_16x16x32_bf16(a, wf1[nt][ks], acc[nt], 0, 0, 0);
      }
      if (lane < 16) {
#pragma unroll
        for (int nt = 0; nt < 4; nt++) *(f32x4*)&red1[w][nt][lane][0] = acc[nt];
      }
    }
    __syncthreads();
    // ---- reduce 8 wave-partials (all 512 threads: 2 layers x 4 gates x 16 ch x 4 b) ----
    {
      int layer = tid >> 8, nt = (tid >> 6) & 3, cc = (tid >> 2) & 15, q = tid & 3;
      const float (*rp)[4][16][4] = layer ? red1 : red0;
      float s = 0.f;
#pragma unroll
      for (int w8 = 0; w8 < 8; w8++) s += rp[w8][nt][cc][q];
      gsum[layer][nt][cc][q] = s;
    }
    __syncthreads();
    // ---- gate nonlinearity + h writes (128 threads) ----
    if (tid < 128) {
      int layer = tid >> 6;
      bool act = layer ? act1 : act0;
      if (act) {
        float gi = gsum[layer][0][gch][gb], gf = gsum[layer][1][gch][gb];
        float gg = gsum[layer][2][gch][gb], go = gsum[layer][3][gch][gb];
        if (layer == 0) {
          const float* x0p = X0 + ((size_t)(gb * 64 + p)) * 4096 + base + gch;
          gi += x0p[0]; gf += x0p[1024]; gg += x0p[2048]; go += x0p[3072];
        } else {
          gi += bs0; gf += bs1; gg += bs2; go += bs3;
        }
        float ii = 1.f / (1.f + __expf(-gi));
        float ff = 1.f / (1.f + __expf(-gf));
        float oo = 1.f / (1.f + __expf(-go));
        float cn = ff * creg + ii * tanhf(gg);
        creg = cn;
        float hn = oo * tanhf(cn);
        if (layer == 0) {
          __hip_atomic_store(&h0h[(size_t)(p + 1) * 4096 + gb * 1024 + base + gch], hn,
                             __ATOMIC_RELAXED, __HIP_MEMORY_SCOPE_AGENT);
        } else {
          __hip_atomic_store(&h1h[(size_t)p * 4096 + gb * 1024 + base + gch], hn,
                             __ATOMIC_RELAXED, __HIP_MEMORY_SCOPE_AGENT);
          hdec[((size_t)(gb * 64 + (p - 1))) * 1024 + base + gch] = hn;
        }
      }
    }
    // ---- arrival: flush h stores (each wave drains own vmcnt before barrier) ----
    asm volatile("s_waitcnt vmcnt(0)" ::: "memory");
    __syncthreads();
    if (tid == 0 && p < 64)
      __hip_atomic_store(&flags[bid], p + 1, __ATOMIC_RELAXED, __HIP_MEMORY_SCOPE_AGENT);
  }
}

// ---------------- joint: out[b,t,u,:] = tanh(encp[b,t,:]+decp[b,u,:]) @ Wout^T + bout ----
// 256 blocks x 512 threads; z-panel in regs; LDS-staged coalesced NT f32 epilogue.
__global__ __launch_bounds__(512) void k_joint(const float* __restrict__ encp,   // (B,T,512)
                                               const float* __restrict__ decp,   // (B,U,512)
                                               const unsigned short* __restrict__ Wout, // (2048,512) bf16
                                               const float* __restrict__ bout,   // (2048) f32
                                               float* __restrict__ out) {        // (B,T,U,2048) f32
  __shared__ unsigned short Wls[2][8192];   // 2 x 16KB: 128 n-rows x 64 k (swizzled)
  __shared__ float C_lds[128][132];         // 67.6 KB staging tile (pad 132 kills bank alias)
  int tid = threadIdx.x;
  int lane = tid & 63, wid = tid >> 6;      // 8 waves
  int bidx = blockIdx.x;
  int b = bidx >> 6, tloc = bidx & 63;
  int t0 = tloc * 2;
  int wm = (wid >> 1) * 32;                 // 4 m-waves x 32 rows
  int wn = (wid & 1) * 64;                  // 2 n-waves x 64 cols
  size_t rowbase = ((size_t)(b * 128 + t0)) * 64;   // block's 128 contiguous (t,u) rows

  // ---- prologue: issue stage of chunk 0 (overlaps with A-build) ----
  {
#pragma unroll
    for (int q = 0; q < 2; q++) {
      int idx = tid + q * 512;
      int n = idx >> 3, sl = idx & 7;
      int ss = sl ^ (n & 7);
      gload_lds16(Wout + (size_t)n * 512 + ss * 8, &Wls[0][idx * 8]);
    }
  }

  // ---- build A panel in registers: 2 m-frags x 16 k-frags, bf16x8 each ----
  bf16x8 afr[32];
#pragma unroll
  for (int mf = 0; mf < 2; mf++) {
    int rr = wm + mf * 16 + (lane & 15);
    int t = t0 + (rr >> 6), u = rr & 63;
    const float* ep = encp + ((size_t)(b * 128 + t)) * 512;
    const float* dp = decp + ((size_t)(b * 64 + u)) * 512;
#pragma unroll
    for (int kf = 0; kf < 16; kf++) {
      int k0 = kf * 32 + ((lane >> 4) << 3);
      bf16x8 v;
#pragma unroll
      for (int j = 0; j < 8; j++) {
        float x = ep[k0 + j] + dp[k0 + j];
        float e = __expf(x + x);
        v[j] = (short)f2bf(1.f - 2.f / (e + 1.f));
      }
      afr[mf * 16 + kf] = v;
    }
  }

  f32x4 acc[2][4];
#pragma unroll
  for (int mf = 0; mf < 2; mf++)
#pragma unroll
    for (int nf = 0; nf < 4; nf++) acc[mf][nf] = (f32x4){0.f, 0.f, 0.f, 0.f};

  // ---- main loop: 16 n-tiles x 8 k-chunks, depth-1 prefetch ----
  for (int c = 0; c < 128; c++) {
    int nt = c >> 3, kc = c & 7;
    __syncthreads();                    // drains vmcnt(0): chunk c is in LDS
    if (c < 127) {
      int c1i = c + 1;
      int nn0 = (c1i >> 3) << 7;
      int kb = (c1i & 7) * 64;
      unsigned short* dst = Wls[c1i & 1];
#pragma unroll
      for (int q = 0; q < 2; q++) {
        int idx = tid + q * 512;
        int n = idx >> 3, sl = idx & 7;
        int ss = sl ^ (n & 7);
        gload_lds16(Wout + (size_t)(nn0 + n) * 512 + kb + ss * 8, dst + idx * 8);
      }
    }
    const unsigned short* Wb = Wls[c & 1];
#pragma unroll
    for (int ks = 0; ks < 2; ks++) {
      bf16x8 bfr[4];
#pragma unroll
      for (int nf = 0; nf < 4; nf++) {
        int n = wn + nf * 16 + (lane & 15);
        int slot = ks * 4 + (lane >> 4);
        int phys = slot ^ (n & 7);
        bfr[nf] = *(const bf16x8*)(Wb + n * 64 + phys * 8);
      }
      int kf = kc * 2 + ks;
#pragma unroll
      for (int mf = 0; mf < 2; mf++)
#pragma unroll
        for (int nf = 0; nf < 4; nf++)
          acc[mf][nf] = __builtin_amdgcn_mfma_f32_16x16x32_bf16(afr[mf * 16 + kf], bfr[nf],
                                                                acc[mf][nf], 0, 0, 0);
    }
    if (kc == 7) {                      // epilogue for this n-tile: stage to LDS, coalesce
      int n0 = nt << 7;
#pragma unroll
      for (int mf = 0; mf < 2; mf++) {
        int rb = wm + mf * 16 + ((lane >> 4) << 2);
#pragma unroll
        for (int nf = 0; nf < 4; nf++) {
          int cc = wn + nf * 16 + (lane & 15);
#pragma unroll
          for (int q = 0; q < 4; q++)
            C_lds[rb + q][cc] = acc[mf][nf][q];
          acc[mf][nf] = (f32x4){0.f, 0.f, 0.f, 0.f};
        }
      }
      __syncthreads();
      // cooperative copy-out: 128 rows x 128 cols f32, f32x4 NT stores, 512B/row segments
      const float* bp = bout + n0;
#pragma unroll
      for (int it = 0; it < 8; it++) {
        int ci = (tid + it * 512) * 4;          // 0..16380
        int row = ci >> 7, col = ci & 127;
        f32x4 v = *(const f32x4*)&C_lds[row][col];
        f32x4 bb = *(const f32x4*)(bp + col);
        v += bb;
        __builtin_nontemporal_store(v, (f32x4*)&out[(rowbase + row) * 2048 + n0 + col]);
      }
      // next iteration's leading __syncthreads() protects C_lds reuse
    }
  }
}

// ---------------- launch ----------------
extern "C" void kernel_launch(void* const* d_in, const int* in_sizes, int n_in,
                              void* d_out, int out_size, void* d_ws, size_t ws_size,
                              hipStream_t stream) {
  const float* hs   = (const float*)d_in[0];
  const int*   ys   = (const int*)d_in[1];
  const float* emb  = (const float*)d_in[2];
  const float* Wih0 = (const float*)d_in[3];
  const float* Whh0 = (const float*)d_in[4];
  const float* bih0 = (const float*)d_in[5];
  const float* bhh0 = (const float*)d_in[6];
  const float* Wih1 = (const float*)d_in[7];
  const float* Whh1 = (const float*)d_in[8];
  const float* bih1 = (const float*)d_in[9];
  const float* bhh1 = (const float*)d_in[10];
  const float* Wenc = (const float*)d_in[11];
  const float* benc = (const float*)d_in[12];
  const float* Wdec = (const float*)d_in[13];
  const float* Wout = (const float*)d_in[14];
  const float* bout = (const float*)d_in[15];

  char* ws = (char*)d_ws;
  float*          eys   = (float*)(ws + 0);            // 256x512 f32        = 524,288
  float*          X0    = (float*)(ws + 524288);       // 256x4096 f32       = 4,194,304
  float*          encp  = (float*)(ws + 4718592);      // 512x512 f32        = 1,048,576
  float*          decp  = (float*)(ws + 5767168);      // 256x512 f32        = 524,288
  float*          h0h   = (float*)(ws + 6291456);      // 65x4096 f32        = 1,064,960
  float*          h1h   = (float*)(ws + 7356416);      // 65x4096 f32        = 1,064,960
  float*          hdec  = (float*)(ws + 8421376);      // 256x1024 f32       = 1,048,576
  int*            flags = (int*)(ws + 9469952);        // 64 ints
  unsigned short* Whh0b = (unsigned short*)(ws + 9502720);   // 4M bf16      = 8,388,608
  unsigned short* Wih1b = (unsigned short*)(ws + 17891328);  // 4M bf16      = 8,388,608
  unsigned short* Whh1b = (unsigned short*)(ws + 26279936);  // 4M bf16      = 8,388,608
  unsigned short* Woutb = (unsigned short*)(ws + 34668544);  // 1M bf16      = 2,097,152
  float*          out   = (float*)d_out;                     // total ws = 36,765,696 B

  // weight conversion (bf16 for LSTM recurrent mats + Wout for global_load_lds)
  k_cvt<<<6656, 256, 0, stream>>>(Whh0, Wih1, Whh1, Wout, Whh0b, Wih1b, Whh1b, Woutb);
  k_prep<<<64, 256, 0, stream>>>(ys, emb, eys, h0h, h1h, flags);
  // X0 = eys @ Wih0^T + bih0 + bhh0   (M=256, N=4096, K=512)
  k_gemm_bias<<<256, 256, 0, stream>>>(eys, Wih0, bih0, bhh0, X0, 256, 4096, 512);
  // encp = hs @ Wenc^T + benc         (M=512, N=512, K=512)
  k_gemm_bias<<<64, 256, 0, stream>>>(hs, Wenc, benc, nullptr, encp, 512, 512, 512);
  // fused LSTM v3: 64 merged blocks, single sync domain
  k_lstm_fused<<<64, 512, 0, stream>>>(X0, h0h, h1h, hdec,
                                       Whh0b, Wih1b, Whh1b, bih1, bhh1, flags);
  // decp = hdec @ Wdec^T              (M=256, N=512, K=1024)
  k_gemm_bias<<<32, 256, 0, stream>>>(hdec, Wdec, nullptr, nullptr, decp, 256, 512, 1024);
  // joint
  k_joint<<<256, 512, 0, stream>>>(encp, decp, Woutb, bout, out);
}

// Round 10
// 686.436 us; speedup vs baseline: 1.0782x; 1.0782x over previous
//
#include <hip/hip_runtime.h>
#include <stdint.h>

typedef short bf16x8 __attribute__((ext_vector_type(8)));
typedef float f32x4 __attribute__((ext_vector_type(4)));

__device__ __forceinline__ unsigned short f2bf(float f) {
  union { float f; unsigned int i; } v; v.f = f;
  unsigned int r = v.i + 0x7FFF + ((v.i >> 16) & 1);
  return (unsigned short)(r >> 16);
}
__device__ __forceinline__ void gload_lds16(const void* g, void* l) {
  __builtin_amdgcn_global_load_lds(
      (const __attribute__((address_space(1))) unsigned int*)g,
      (__attribute__((address_space(3))) unsigned int*)l,
      16, 0, 0);
}

// ---------------- convert f32 weights -> bf16 (Whh0, Wih1, Whh1, Wout) ----------------
__global__ __launch_bounds__(256) void k_cvt(const float* __restrict__ s0, const float* __restrict__ s1,
                                             const float* __restrict__ s2, const float* __restrict__ s3,
                                             unsigned short* __restrict__ d0, unsigned short* __restrict__ d1,
                                             unsigned short* __restrict__ d2, unsigned short* __restrict__ d3) {
  int j = blockIdx.x * 256 + threadIdx.x;   // 6656*256 = 1,703,936 vec8 jobs exactly
  const float* s; unsigned short* d; int o;
  if (j < 524288)       { s = s0; d = d0; o = j; }
  else if (j < 1048576) { s = s1; d = d1; o = j - 524288; }
  else if (j < 1572864) { s = s2; d = d2; o = j - 1048576; }
  else                  { s = s3; d = d3; o = j - 1572864; }
  size_t off = (size_t)o * 8;
  f32x4 v0 = *(const f32x4*)(s + off);
  f32x4 v1 = *(const f32x4*)(s + off + 4);
  bf16x8 r;
#pragma unroll
  for (int k = 0; k < 4; k++) { r[k] = (short)f2bf(v0[k]); r[4 + k] = (short)f2bf(v1[k]); }
  *(bf16x8*)(d + off) = r;
}

// ---------------- prep: embedding gather (f32) + zero state + zero flags ----------------
__global__ __launch_bounds__(256) void k_prep(const int* __restrict__ ys,
                                              const float* __restrict__ embed,
                                              float* __restrict__ eys,
                                              float* __restrict__ h0h, float* __restrict__ h1h,
                                              int* __restrict__ flags) {
  int idx = blockIdx.x * 256 + threadIdx.x;   // 16384 threads
  int row = idx >> 6;
  int e = (idx & 63) * 8;
  int y = ys[row];
  f32x4 v0 = {0.f, 0.f, 0.f, 0.f}, v1 = {0.f, 0.f, 0.f, 0.f};
  if (y != 0) {
    v0 = *(const f32x4*)(embed + (size_t)y * 512 + e);
    v1 = *(const f32x4*)(embed + (size_t)y * 512 + e + 4);
  }
  *(f32x4*)(eys + (size_t)row * 512 + e) = v0;
  *(f32x4*)(eys + (size_t)row * 512 + e + 4) = v1;
  if (idx < 4096) { h0h[idx] = 0.f; h1h[idx] = 0.f; }
  if (idx < 64) flags[idx] = 0;
}

// -------- generic small GEMM: C(f32 MxN) = A(f32 MxK) @ W(f32 NxK)^T + b1 + b2 --------
__global__ __launch_bounds__(256) void k_gemm_bias(const float* __restrict__ A,
                                                   const float* __restrict__ W,
                                                   const float* __restrict__ b1,
                                                   const float* __restrict__ b2,
                                                   float* __restrict__ C,
                                                   int M, int N, int K) {
  __shared__ unsigned short Als[64][40];
  __shared__ unsigned short Wls[64][40];
  int tid = threadIdx.x;
  int lane = tid & 63, wid = tid >> 6;
  int mtiles = M >> 6;
  int mt = blockIdx.x % mtiles, nt = blockIdx.x / mtiles;
  int srow = tid >> 2, sseg = tid & 3;
  f32x4 acc[4];
#pragma unroll
  for (int nf = 0; nf < 4; nf++) acc[nf] = (f32x4){0.f, 0.f, 0.f, 0.f};

  for (int kc = 0; kc < K; kc += 32) {
    const float* ap = A + (size_t)(mt * 64 + srow) * K + kc + sseg * 8;
    const float* wp = W + (size_t)(nt * 64 + srow) * K + kc + sseg * 8;
    f32x4 a0 = *(const f32x4*)ap, a1 = *(const f32x4*)(ap + 4);
    f32x4 w0 = *(const f32x4*)wp, w1 = *(const f32x4*)(wp + 4);
    bf16x8 av, wv;
#pragma unroll
    for (int k = 0; k < 4; k++) {
      av[k] = (short)f2bf(a0[k]); av[4 + k] = (short)f2bf(a1[k]);
      wv[k] = (short)f2bf(w0[k]); wv[4 + k] = (short)f2bf(w1[k]);
    }
    __syncthreads();
    *(bf16x8*)(&Als[srow][sseg * 8]) = av;
    *(bf16x8*)(&Wls[srow][sseg * 8]) = wv;
    __syncthreads();
    bf16x8 af = *(const bf16x8*)(&Als[wid * 16 + (lane & 15)][(lane >> 4) * 8]);
#pragma unroll
    for (int nf = 0; nf < 4; nf++) {
      bf16x8 bf = *(const bf16x8*)(&Wls[nf * 16 + (lane & 15)][(lane >> 4) * 8]);
      acc[nf] = __builtin_amdgcn_mfma_f32_16x16x32_bf16(af, bf, acc[nf], 0, 0, 0);
    }
  }
  int rloc = (lane >> 4) * 4;
  int col0 = lane & 15;
#pragma unroll
  for (int nf = 0; nf < 4; nf++) {
    int n = nt * 64 + nf * 16 + col0;
    float bias = 0.f;
    if (b1) bias += b1[n];
    if (b2) bias += b2[n];
#pragma unroll
    for (int r = 0; r < 4; r++) {
      int m = mt * 64 + wid * 16 + rloc + r;
      C[(size_t)m * N + n] = acc[nf][r] + bias;
    }
  }
}

// ---------------- fused LSTM v3: 64 merged blocks, single sync domain ----------------
__global__ __launch_bounds__(512, 2) void k_lstm_fused(
    const float* __restrict__ X0,            // (B,U,4096)  eys@Wih0^T + bih0 + bhh0
    float* __restrict__ h0h,                 // (65,B,1024)
    float* __restrict__ h1h,                 // (65,B,1024)
    float* __restrict__ hdec,                // (B,U,1024) f32
    const unsigned short* __restrict__ W_hh0,
    const unsigned short* __restrict__ W_ih1,
    const unsigned short* __restrict__ W_hh1,
    const float* __restrict__ b_ih1,
    const float* __restrict__ b_hh1,
    int* __restrict__ flags) {               // 64 flags
  __shared__ unsigned short X_lds[4][2064];  // 4 batches x 2048 k (+16 pad)
  __shared__ float red0[8][4][16][4];        // 8 KB
  __shared__ float red1[8][4][16][4];        // 8 KB
  __shared__ float gsum[2][4][16][4];        // 2 KB
  int tid = threadIdx.x;
  int lane = tid & 63, w = tid >> 6;
  int bid = blockIdx.x;                      // 0..63
  int base = bid * 16;

  // ---- preload weight B-frags (fragment scheme identical to passing r5-r8 kernel) ----
  bf16x8 wf0[4][4];    // [gate][ks], layer0: K=128 per wave
  bf16x8 wf1[4][8];    // layer1: K=256 per wave (k<1024 -> Wih1, else Whh1)
  int ch = lane & 15;
  int kb0 = w * 128, kb1 = w * 256;
  int klo = (lane >> 4) << 3;
#pragma unroll
  for (int nt = 0; nt < 4; nt++) {
    int grow = nt * 1024 + base + ch;
#pragma unroll
    for (int ks = 0; ks < 4; ks++)
      wf0[nt][ks] = *(const bf16x8*)(W_hh0 + (size_t)grow * 1024 + kb0 + ks * 32 + klo);
#pragma unroll
    for (int ks = 0; ks < 8; ks++) {
      int k = kb1 + ks * 32 + klo;
      const unsigned short* src = (k < 1024) ? (W_ih1 + (size_t)grow * 1024 + k)
                                             : (W_hh1 + (size_t)grow * 1024 + (k - 1024));
      wf1[nt][ks] = *(const bf16x8*)src;
    }
  }

  // gate-thread persistent state: tid<64 -> layer0 (ch=tid>>2, b=tid&3); 64..127 -> layer1
  float creg = 0.f;
  float bs0 = 0.f, bs1 = 0.f, bs2 = 0.f, bs3 = 0.f;
  int gch = (tid & 63) >> 2, gb = tid & 3;
  if (tid >= 64 && tid < 128) {
    int c = base + gch;
    bs0 = b_ih1[c] + b_hh1[c];
    bs1 = b_ih1[1024 + c] + b_hh1[1024 + c];
    bs2 = b_ih1[2048 + c] + b_hh1[2048 + c];
    bs3 = b_ih1[3072 + c] + b_hh1[3072 + c];
  }

  int ar = ch & 3;                           // clamped A-row (batch); D rows 4-15 unused
  for (int p = 0; p <= 64; p++) {
    bool act0 = (p < 64), act1 = (p >= 1);
    if (p > 0) {
      if (w == 0) {
        while (true) {
          int f = __hip_atomic_load(&flags[lane], __ATOMIC_RELAXED, __HIP_MEMORY_SCOPE_AGENT);
          if (__all(f >= p)) break;
          __builtin_amdgcn_s_sleep(1);
        }
      }
      __syncthreads();
    }
    // ---- stage X = [h0h[p] | h1h[p-1]] as bf16, 4x2048 ----
    {
      int b = tid >> 7, k0 = (tid & 127) * 16;
      if (k0 < 1024 || act1) {
        const float* fsrc = (k0 < 1024) ? (h0h + (size_t)p * 4096 + b * 1024 + k0)
                                        : (h1h + (size_t)(p - 1) * 4096 + b * 1024 + (k0 - 1024));
        const unsigned long long* s8 = (const unsigned long long*)fsrc;
        unsigned long long v[8];
#pragma unroll
        for (int i = 0; i < 8; i++)
          v[i] = __hip_atomic_load(s8 + i, __ATOMIC_RELAXED, __HIP_MEMORY_SCOPE_AGENT);
        bf16x8 r0, r1;
#pragma unroll
        for (int i = 0; i < 4; i++) {
          union { unsigned long long u; float f[2]; } cv; cv.u = v[i];
          r0[2 * i] = (short)f2bf(cv.f[0]); r0[2 * i + 1] = (short)f2bf(cv.f[1]);
        }
#pragma unroll
        for (int i = 0; i < 4; i++) {
          union { unsigned long long u; float f[2]; } cv; cv.u = v[4 + i];
          r1[2 * i] = (short)f2bf(cv.f[0]); r1[2 * i + 1] = (short)f2bf(cv.f[1]);
        }
        *(bf16x8*)&X_lds[b][k0] = r0;
        *(bf16x8*)&X_lds[b][k0 + 8] = r1;
      }
    }
    __syncthreads();

    if (act0) {
      f32x4 acc[4];
#pragma unroll
      for (int nt = 0; nt < 4; nt++) acc[nt] = (f32x4){0.f, 0.f, 0.f, 0.f};
#pragma unroll
      for (int ks = 0; ks < 4; ks++) {
        bf16x8 a = *(const bf16x8*)&X_lds[ar][kb0 + ks * 32 + klo];
#pragma unroll
        for (int nt = 0; nt < 4; nt++)
          acc[nt] = __builtin_amdgcn_mfma_f32_16x16x32_bf16(a, wf0[nt][ks], acc[nt], 0, 0, 0);
      }
      if (lane < 16) {
#pragma unroll
        for (int nt = 0; nt < 4; nt++) *(f32x4*)&red0[w][nt][lane][0] = acc[nt];
      }
    }
    if (act1) {
      f32x4 acc[4];
#pragma unroll
      for (int nt = 0; nt < 4; nt++) acc[nt] = (f32x4){0.f, 0.f, 0.f, 0.f};
#pragma unroll
      for (int ks = 0; ks < 8; ks++) {
        bf16x8 a = *(const bf16x8*)&X_lds[ar][kb1 + ks * 32 + klo];
#pragma unroll
        for (int nt = 0; nt < 4; nt++)
          acc[nt] = __builtin_amdgcn_mfma_f32_16x16x32_bf16(a, wf1[nt][ks], acc[nt], 0, 0, 0);
      }
      if (lane < 16) {
#pragma unroll
        for (int nt = 0; nt < 4; nt++) *(f32x4*)&red1[w][nt][lane][0] = acc[nt];
      }
    }
    __syncthreads();
    {
      int layer = tid >> 8, nt = (tid >> 6) & 3, cc = (tid >> 2) & 15, q = tid & 3;
      const float (*rp)[4][16][4] = layer ? red1 : red0;
      float s = 0.f;
#pragma unroll
      for (int w8 = 0; w8 < 8; w8++) s += rp[w8][nt][cc][q];
      gsum[layer][nt][cc][q] = s;
    }
    __syncthreads();
    if (tid < 128) {
      int layer = tid >> 6;
      bool act = layer ? act1 : act0;
      if (act) {
        float gi = gsum[layer][0][gch][gb], gf = gsum[layer][1][gch][gb];
        float gg = gsum[layer][2][gch][gb], go = gsum[layer][3][gch][gb];
        if (layer == 0) {
          const float* x0p = X0 + ((size_t)(gb * 64 + p)) * 4096 + base + gch;
          gi += x0p[0]; gf += x0p[1024]; gg += x0p[2048]; go += x0p[3072];
        } else {
          gi += bs0; gf += bs1; gg += bs2; go += bs3;
        }
        float ii = 1.f / (1.f + __expf(-gi));
        float ff = 1.f / (1.f + __expf(-gf));
        float oo = 1.f / (1.f + __expf(-go));
        float cn = ff * creg + ii * tanhf(gg);
        creg = cn;
        float hn = oo * tanhf(cn);
        if (layer == 0) {
          __hip_atomic_store(&h0h[(size_t)(p + 1) * 4096 + gb * 1024 + base + gch], hn,
                             __ATOMIC_RELAXED, __HIP_MEMORY_SCOPE_AGENT);
        } else {
          __hip_atomic_store(&h1h[(size_t)p * 4096 + gb * 1024 + base + gch], hn,
                             __ATOMIC_RELAXED, __HIP_MEMORY_SCOPE_AGENT);
          hdec[((size_t)(gb * 64 + (p - 1))) * 1024 + base + gch] = hn;
        }
      }
    }
    asm volatile("s_waitcnt vmcnt(0)" ::: "memory");
    __syncthreads();
    if (tid == 0 && p < 64)
      __hip_atomic_store(&flags[bid], p + 1, __ATOMIC_RELAXED, __HIP_MEMORY_SCOPE_AGENT);
  }
}

// ---------------- joint v3: 512 blocks x 64-row tiles, depth-3 chunk pipeline ----------
// Counted vmcnt + raw s_barrier (T3/T4): Wout chunk loads stay in flight across barriers.
// 4 x 16KB LDS buffers; 2 blocks/CU. Epilogue: direct NT f32 stores (64B sectors).
__global__ __launch_bounds__(512, 4) void k_joint(const float* __restrict__ encp,   // (B,T,512)
                                                  const float* __restrict__ decp,   // (B,U,512)
                                                  const unsigned short* __restrict__ Wout, // (2048,512) bf16
                                                  const float* __restrict__ bout,   // (2048) f32
                                                  float* __restrict__ out) {        // (B,T,U,2048) f32
  __shared__ unsigned short Wls[4][8192];   // 4 buffers x 16KB: 128 n-rows x 64 k (swizzled)
  int tid = threadIdx.x;
  int lane = tid & 63, wid = tid >> 6;      // 8 waves
  int bidx = blockIdx.x;                    // 512 blocks: one (b, t) each
  int b = bidx >> 7, tloc = bidx & 127;
  int wm = (wid >> 1) * 16;                 // 4 m-positions x 16 rows (u)
  int wn = (wid & 1) * 64;                  // 2 n-halves x 64 cols
  size_t rowbase = ((size_t)(b * 128 + tloc)) * 64;

#define STAGE_CHUNK(cg)                                                        \
  {                                                                            \
    int nn0_ = ((cg) >> 3) << 7;                                               \
    int kb_ = ((cg) & 7) * 64;                                                 \
    unsigned short* dst_ = Wls[(cg) & 3];                                      \
    _Pragma("unroll")                                                          \
    for (int q_ = 0; q_ < 2; q_++) {                                           \
      int idx_ = tid + q_ * 512;                                               \
      int n_ = idx_ >> 3, sl_ = idx_ & 7;                                      \
      int ss_ = sl_ ^ (n_ & 7);                                                \
      gload_lds16(Wout + (size_t)(nn0_ + n_) * 512 + kb_ + ss_ * 8, dst_ + idx_ * 8); \
    }                                                                          \
  }

  // ---- prologue: 3 chunks in flight before/during A-build ----
  STAGE_CHUNK(0)
  STAGE_CHUNK(1)
  STAGE_CHUNK(2)

  // ---- build A panel in registers: 16 rows (u) x 512 k per wave ----
  bf16x8 afr[16];
  {
    int u = wm + (lane & 15);
    const float* ep = encp + ((size_t)(b * 128 + tloc)) * 512;
    const float* dp = decp + ((size_t)(b * 64 + u)) * 512;
#pragma unroll
    for (int kf = 0; kf < 16; kf++) {
      int k0 = kf * 32 + ((lane >> 4) << 3);
      bf16x8 v;
#pragma unroll
      for (int j = 0; j < 8; j++) {
        float x = ep[k0 + j] + dp[k0 + j];
        float e = __expf(x + x);
        v[j] = (short)f2bf(1.f - 2.f / (e + 1.f));
      }
      afr[kf] = v;
    }
  }

  f32x4 acc[4];
#pragma unroll
  for (int nf = 0; nf < 4; nf++) acc[nf] = (f32x4){0.f, 0.f, 0.f, 0.f};

  // ---- main loop: 128 chunks (16 n-tiles x 8 k-chunks), depth-3, counted vmcnt ----
  for (int c = 0; c < 128; c++) {
    // own-wave chunk-c loads retired (keep <=2 newer chunks = 4 ops in flight), then sync
    asm volatile("s_waitcnt vmcnt(4)" ::: "memory");
    __builtin_amdgcn_s_barrier();
    const unsigned short* Wb = Wls[c & 3];
    int kc = c & 7;
#pragma unroll
    for (int ks = 0; ks < 2; ks++) {
      bf16x8 bfr[4];
#pragma unroll
      for (int nf = 0; nf < 4; nf++) {
        int n = wn + nf * 16 + (lane & 15);
        int slot = ks * 4 + (lane >> 4);
        int phys = slot ^ (n & 7);
        bfr[nf] = *(const bf16x8*)(Wb + n * 64 + phys * 8);
      }
      int kf = kc * 2 + ks;
#pragma unroll
      for (int nf = 0; nf < 4; nf++)
        acc[nf] = __builtin_amdgcn_mfma_f32_16x16x32_bf16(afr[kf], bfr[nf], acc[nf], 0, 0, 0);
    }
    if (kc == 7) {                      // epilogue for this n-tile: direct NT stores
      int n0 = (c >> 3) << 7;
      int rb = wm + ((lane >> 4) << 2);
#pragma unroll
      for (int nf = 0; nf < 4; nf++) {
        int o = n0 + wn + nf * 16 + (lane & 15);
        float bb = bout[o];
#pragma unroll
        for (int q = 0; q < 4; q++)
          __builtin_nontemporal_store(acc[nf][q] + bb, &out[(rowbase + rb + q) * 2048 + o]);
        acc[nf] = (f32x4){0.f, 0.f, 0.f, 0.f};
      }
    }
    if (c < 125) STAGE_CHUNK(c + 3)
  }
#undef STAGE_CHUNK
}

// ---------------- launch ----------------
extern "C" void kernel_launch(void* const* d_in, const int* in_sizes, int n_in,
                              void* d_out, int out_size, void* d_ws, size_t ws_size,
                              hipStream_t stream) {
  const float* hs   = (const float*)d_in[0];
  const int*   ys   = (const int*)d_in[1];
  const float* emb  = (const float*)d_in[2];
  const float* Wih0 = (const float*)d_in[3];
  const float* Whh0 = (const float*)d_in[4];
  const float* bih0 = (const float*)d_in[5];
  const float* bhh0 = (const float*)d_in[6];
  const float* Wih1 = (const float*)d_in[7];
  const float* Whh1 = (const float*)d_in[8];
  const float* bih1 = (const float*)d_in[9];
  const float* bhh1 = (const float*)d_in[10];
  const float* Wenc = (const float*)d_in[11];
  const float* benc = (const float*)d_in[12];
  const float* Wdec = (const float*)d_in[13];
  const float* Wout = (const float*)d_in[14];
  const float* bout = (const float*)d_in[15];

  char* ws = (char*)d_ws;
  float*          eys   = (float*)(ws + 0);            // 256x512 f32        = 524,288
  float*          X0    = (float*)(ws + 524288);       // 256x4096 f32       = 4,194,304
  float*          encp  = (float*)(ws + 4718592);      // 512x512 f32        = 1,048,576
  float*          decp  = (float*)(ws + 5767168);      // 256x512 f32        = 524,288
  float*          h0h   = (float*)(ws + 6291456);      // 65x4096 f32        = 1,064,960
  float*          h1h   = (float*)(ws + 7356416);      // 65x4096 f32        = 1,064,960
  float*          hdec  = (float*)(ws + 8421376);      // 256x1024 f32       = 1,048,576
  int*            flags = (int*)(ws + 9469952);        // 64 ints
  unsigned short* Whh0b = (unsigned short*)(ws + 9502720);   // 4M bf16      = 8,388,608
  unsigned short* Wih1b = (unsigned short*)(ws + 17891328);  // 4M bf16      = 8,388,608
  unsigned short* Whh1b = (unsigned short*)(ws + 26279936);  // 4M bf16      = 8,388,608
  unsigned short* Woutb = (unsigned short*)(ws + 34668544);  // 1M bf16      = 2,097,152
  float*          out   = (float*)d_out;                     // total ws = 36,765,696 B

  // weight conversion (bf16 for LSTM recurrent mats + Wout for global_load_lds)
  k_cvt<<<6656, 256, 0, stream>>>(Whh0, Wih1, Whh1, Wout, Whh0b, Wih1b, Whh1b, Woutb);
  k_prep<<<64, 256, 0, stream>>>(ys, emb, eys, h0h, h1h, flags);
  // X0 = eys @ Wih0^T + bih0 + bhh0   (M=256, N=4096, K=512)
  k_gemm_bias<<<256, 256, 0, stream>>>(eys, Wih0, bih0, bhh0, X0, 256, 4096, 512);
  // encp = hs @ Wenc^T + benc         (M=512, N=512, K=512)
  k_gemm_bias<<<64, 256, 0, stream>>>(hs, Wenc, benc, nullptr, encp, 512, 512, 512);
  // fused LSTM v3: 64 merged blocks, single sync domain
  k_lstm_fused<<<64, 512, 0, stream>>>(X0, h0h, h1h, hdec,
                                       Whh0b, Wih1b, Whh1b, bih1, bhh1, flags);
  // decp = hdec @ Wdec^T              (M=256, N=512, K=1024)
  k_gemm_bias<<<32, 256, 0, stream>>>(hdec, Wdec, nullptr, nullptr, decp, 256, 512, 1024);
  // joint v3: depth-3 pipelined chunks, 2 blocks/CU
  k_joint<<<512, 512, 0, stream>>>(encp, decp, Woutb, bout, out);
}